// Round 8
// baseline (29.934 us; speedup 1.0000x reference)
//
#include <hip/hip_runtime.h>

namespace {

constexpr float ETA_C = 1.5f;
constexpr float PI_F  = 3.14159265358979323846f;
constexpr int   BLOCK = 256;

__device__ __forceinline__ float fast_rcp(float x)  { return __builtin_amdgcn_rcpf(x); }
__device__ __forceinline__ float fast_sqrt(float x) { return __builtin_amdgcn_sqrtf(x); }
__device__ __forceinline__ float fast_rsq(float x)  { return __builtin_amdgcn_rsqf(x); }

__device__ __forceinline__ float schlick_w(float c) {
    float m = fminf(fmaxf(1.0f - c, 0.0f), 1.0f);
    float m2 = m * m;
    return m2 * m2 * m;  // m^5
}

// Max-TLP: 1 point/thread, 17 dword loads (4B/lane, fully coalesced),
// ~20 VGPR -> 8 waves/SIMD, 8192 blocks = 32 wg/CU across 4 generations.
// Trend so far: 8pt 34.5us, 4pt 33.7us, 2pt 29.75us -> TLP is the lever.
__global__ void renderer_kernel(
    const float* __restrict__ light_p,
    const float* __restrict__ dist_p,
    const float* __restrict__ norm_p,
    const float* __restrict__ view_p,
    const float* __restrict__ anis_p,
    const float* __restrict__ rough_p,
    const float* __restrict__ met_p,
    const float* __restrict__ tint_p,
    const float* __restrict__ salb_p,
    const float* __restrict__ dalb_p,
    float* __restrict__ out_p,
    int n_pts)
{
    const int t = blockIdx.x * BLOCK + threadIdx.x;   // one thread = one point
    if (t >= n_pts) return;

    // ---- 17 coalesced dword loads ----
    const float dist = dist_p[t];
    const float anv  = anis_p[t];
    const float rgv  = rough_p[t];
    const float mtv  = met_p[t];
    const float ttv  = tint_p[t];

    const float nx = norm_p[3 * t + 0];
    const float ny = norm_p[3 * t + 1];
    const float nz = norm_p[3 * t + 2];
    const float vx = view_p[3 * t + 0];
    const float vy = view_p[3 * t + 1];
    const float vz = view_p[3 * t + 2];
    const float sxx = salb_p[3 * t + 0];
    const float syy = salb_p[3 * t + 1];
    const float szz = salb_p[3 * t + 2];
    const float bxx = dalb_p[3 * t + 0];
    const float byy = dalb_p[3 * t + 1];
    const float bzz = dalb_p[3 * t + 2];

    const float light = light_p[0];

    // Proven lever (R5/R7): all loads issued before any compute.
    __builtin_amdgcn_sched_barrier(0);

    const float cosv = nx * vx + ny * vy + nz * vz;
    const float anis  = fmaxf(anv, 1e-5f);
    const float rough = fmaxf(rgv, 1e-5f);
    const float met   = fmaxf(mtv, 1e-5f);
    const float tint  = fmaxf(ttv, 1e-6f);
    const float sa[3] = {fmaxf(sxx, 1e-5f), fmaxf(syy, 1e-5f), fmaxf(szz, 1e-5f)};
    const float da[3] = {fmaxf(bxx, 1e-5f), fmaxf(byy, 1e-5f), fmaxf(bzz, 1e-5f)};

    const float c2 = cosv * cosv;
    const float ci = fabsf(cosv);

    // anisotropic GGX alphas
    const float r2 = fast_sqrt(rough);
    const float w  = 1.0f - 0.9f * anis;
    const float alpha_u = fmaxf(r2 * fast_rsq(w),  1e-4f);
    const float alpha_v = fmaxf(r2 * fast_sqrt(w), 1e-4f);

    // fresnel_dielectric(cos, 1.5)
    const float scale  = (cosv > 0.0f) ? (1.0f / ETA_C) : ETA_C;
    const float ct_sqr = 1.0f - (1.0f - c2) * scale * scale;
    const float ctf = fast_sqrt(ct_sqr);
    const float rs  = (ci - ETA_C * ctf) * fast_rcp(ci + ETA_C * ctf);
    const float rp  = (ETA_C * ci - ctf) * fast_rcp(ETA_C * ci + ctf);
    const float f_die = 0.5f * (rs * rs + rp * rp);

    // D term (module passes eta as alpha; preserved)
    const float a2 = ETA_C * ETA_C;
    const float root_d = c2 + (1.0f - c2) * (1.0f / (a2 + 1e-10f));
    const float d_den  = PI_F * a2 * root_d * root_d + 1e-10f;

    // G term
    const float sin_t = fast_sqrt(fmaxf(1.0f - c2, 0.0f));
    const float tan_t = sin_t * fast_rcp(cosv + 1e-10f);
    const float ru  = alpha_u * tan_t;
    const float rw  = alpha_v * tan_t;
    const float g_u = 2.0f * fast_rcp(1.0f + fast_sqrt(ru * ru + 1.0f));
    const float g_v = 2.0f * fast_rcp(1.0f + fast_sqrt(rw * rw + 1.0f));
    const float g_spec = g_u * g_v;

    const float lum = light * fast_rcp(dist * dist + 1e-10f);
    const float eta_it = (cosv > 0.0f) ? ETA_C : (1.0f / ETA_C);

    // calc_schlick (eta clamped to 0.99999 -> always val_neq1 branch)
    const float eti2 = 0.99999f * 0.99999f;
    const float ct_s = fast_sqrt(1.0f - (1.0f - c2) * eti2);
    const float sw_ct = schlick_w(ct_s);

    float f0s = (eta_it - 1.0f) * fast_rcp(eta_it + 1.0f);
    f0s = f0s * f0s;

    // diffuse + retro-reflection
    const float fw = schlick_w(ci);
    float f_diff = 1.0f - 0.5f * fw;
    f_diff *= f_diff;
    const float alpha_d = 1.0f - rough;
    const float rr = 2.0f * alpha_d * c2;
    const float f_retro = rr * (2.0f * fw + fw * fw * (rr - 1.0f));
    const float one_m_met = 1.0f - met;
    const float diff_com = one_m_met * ci * (1.0f / PI_F) * (f_diff + f_retro);

    const float spec_com = g_spec * fast_rcp(d_den * 4.0f * ci);

    const float rcp_lum = fast_rcp(lum);
    const float lum_pos = (lum > 0.0f) ? 1.0f : 0.0f;

    float o[3];
#pragma unroll
    for (int k = 0; k < 3; ++k) {
        float fs = (sw_ct * (1.0f - sa[k]) + sa[k]) * met;
        const float c_tint = lum_pos * (sa[k] * rcp_lum) + (1.0f - lum_pos);
        const float f0t = c_tint * f0s;
        fs += one_m_met * tint * (sw_ct * (1.0f - f0t) + f0t);
        const float f_princ = one_m_met * (1.0f - tint) * (f_die * sa[k]) + fs;
        o[k] = f_princ * spec_com + diff_com * da[k];
    }

    // nontemporal dword stores (write-once data; keeps WRITE_SIZE at 24MB)
    __builtin_nontemporal_store(o[0], out_p + 3 * t + 0);
    __builtin_nontemporal_store(o[1], out_p + 3 * t + 1);
    __builtin_nontemporal_store(o[2], out_p + 3 * t + 2);
}

}  // namespace

extern "C" void kernel_launch(void* const* d_in, const int* in_sizes, int n_in,
                              void* d_out, int out_size, void* d_ws, size_t ws_size,
                              hipStream_t stream) {
    (void)n_in; (void)out_size; (void)d_ws; (void)ws_size;
    // input order per setup_inputs():
    // 0 light(1) 1 distance(N) 2 normal(N,3) 3 viewdir(N,3) 4 anisotropic(N)
    // 5 specular_roughness(N) 6 metallic(N) 7 clearcoat(N, UNUSED)
    // 8 spec_tint(N) 9 specular_albedo(N,3) 10 diffuse_albedo(N,3)
    const float* light_p = (const float*)d_in[0];
    const float* dist_p  = (const float*)d_in[1];
    const float* norm_p  = (const float*)d_in[2];
    const float* view_p  = (const float*)d_in[3];
    const float* anis_p  = (const float*)d_in[4];
    const float* rough_p = (const float*)d_in[5];
    const float* met_p   = (const float*)d_in[6];
    const float* tint_p  = (const float*)d_in[8];
    const float* salb_p  = (const float*)d_in[9];
    const float* dalb_p  = (const float*)d_in[10];
    float* out_p = (float*)d_out;

    const int n_pts = in_sizes[1];          // N = 2,097,152
    const int grid  = (n_pts + BLOCK - 1) / BLOCK;   // 8192 blocks

    renderer_kernel<<<grid, BLOCK, 0, stream>>>(
        light_p, dist_p, norm_p, view_p, anis_p, rough_p, met_p, tint_p,
        salb_p, dalb_p, out_p, n_pts);
}